// Round 1
// baseline (282.145 us; speedup 1.0000x reference)
//
#include <hip/hip_runtime.h>

#define NBATCH 32
#define NFEAT 48
#define C1c 6
#define LRC 42
#define HH 128
#define WW 128
#define HWSZ 16384
#define NP 81
#define NQ 64

// workspace layout (in floats)
#define OFF_PM   0                      // 81*64 = 5184
#define OFF_GAP  5184                   // 32*42 = 1344
#define OFF_K    6528                   // 64*64 = 4096
#define OFF_ATTN 10624                  // 1344
#define OFF_HR   11968                  // 32*6*16384 = 3145728
// total = 3157696 floats = 12.63 MB

// ---------------- K1: per-pixel softmax over 81 ch, binned into pm_sum[81][64] ----------------
__global__ __launch_bounds__(512) void k_softmax_pm(const float* __restrict__ logits,
                                                    float* __restrict__ pm_sum) {
    __shared__ float lds[NP * NQ];
    for (int i = threadIdx.x; i < NP * NQ; i += 512) lds[i] = 0.f;
    __syncthreads();
    const int x    = threadIdx.x & 127;
    const int rloc = threadIdx.x >> 7;   // 0..3
    const int lane = threadIdx.x & 63;
    for (int u = 0; u < 4; ++u) {
        int row = (blockIdx.x * 4 + u) * 4 + rloc;   // 0..4095
        int b = row >> 7, y = row & 127;
        const float* base = logits + (size_t)b * NP * HWSZ + y * WW + x;
        float ev[NP];
        float s = 0.f;
#pragma unroll
        for (int p = 0; p < NP; ++p) { ev[p] = __expf(base[(size_t)p * HWSZ]); s += ev[p]; }
        float inv = 1.f / s;
#pragma unroll
        for (int p = 0; p < NP; ++p) {
            float e = ev[p] * inv;
            e += __shfl_xor(e, 8);
            e += __shfl_xor(e, 16);
            e += __shfl_xor(e, 32);
            if (lane < 8) atomicAdd(&lds[p * NQ + ((y & 7) << 3) + lane], e);
        }
    }
    __syncthreads();
    for (int i = threadIdx.x; i < NP * NQ; i += 512) atomicAdd(&pm_sum[i], lds[i]);
}

// ---------------- K2: gap_sum[b][c] = sum over HxW of feat[b, 6+c] ----------------
__global__ __launch_bounds__(256) void k_gap(const float* __restrict__ feat,
                                             float* __restrict__ gap) {
    int bid = blockIdx.x;
    int b = bid / LRC, c = bid % LRC;
    const float* p = feat + ((size_t)b * NFEAT + C1c + c) * HWSZ;
    float s = 0.f;
    for (int i = threadIdx.x; i < HWSZ; i += 256) s += p[i];
    s += __shfl_xor(s, 1);  s += __shfl_xor(s, 2);  s += __shfl_xor(s, 4);
    s += __shfl_xor(s, 8);  s += __shfl_xor(s, 16); s += __shfl_xor(s, 32);
    __shared__ float w4[4];
    if ((threadIdx.x & 63) == 0) w4[threadIdx.x >> 6] = s;
    __syncthreads();
    if (threadIdx.x == 0) gap[bid] = w4[0] + w4[1] + w4[2] + w4[3];
}

// ---------------- K3: build K (64x64) and attn (32x42) ----------------
__global__ __launch_bounds__(256) void k_small(const float* __restrict__ pm_sum,
                                               const float* __restrict__ gap_sum,
                                               const float* __restrict__ sigx,
                                               const float* __restrict__ sigy,
                                               const float* __restrict__ opac,
                                               const float* __restrict__ rho,
                                               const float* __restrict__ w_v2,
                                               float* __restrict__ Kmat,
                                               float* __restrict__ attn) {
    int tid = threadIdx.x;
    if (tid < 64) {
        int q = tid;
        float wsx = 0.f, wsy = 0.f, wop = 0.f, wr = 0.f;
        for (int p = 0; p < NP; ++p) {
            float pv = pm_sum[p * NQ + q] * (1.f / 8192.f);
            wsx += sigx[p] * pv;
            wsy += sigy[p] * pv;
            wop += opac[p] * pv;
            wr  += rho[p]  * pv;
        }
        float a = wsx * wsx, d = wsy * wsy, bc = wr * wsx * wsy;
        float det = a * d - bc * bc;
        float i00 = d / det, i01 = -bc / det, i11 = a / det;
        int iq = q >> 3, jq = q & 7;
        for (int h = 0; h < 8; ++h)
            for (int w = 0; w < 8; ++w) {
                int ki = h - iq + 2, kj = w - jq + 2;
                float val = 0.f;
                if (ki >= 0 && ki < 5 && kj >= 0 && kj < 5) {
                    float xx = -5.f + 2.5f * ki, yy = -5.f + 2.5f * kj;
                    val = wop * __expf(-0.5f * (i00 * xx * xx + 2.f * i01 * xx * yy + i11 * yy * yy));
                }
                Kmat[(q << 6) + (h << 3) + w] = val;
            }
    }
    for (int i = tid; i < NBATCH * LRC; i += 256) {
        int b = i / LRC, co = i % LRC;
        float s = 0.f;
        for (int ci = 0; ci < LRC; ++ci) s += w_v2[co * LRC + ci] * gap_sum[b * LRC + ci];
        s *= (1.f / 16384.f);
        attn[i] = 1.f / (1.f + __expf(-s));
    }
}

// ---------------- K4: hr = (colors @ K) * V1, materialized to ws ----------------
__global__ __launch_bounds__(256) void k_hr(const float* __restrict__ feat,
                                            const float* __restrict__ V,
                                            const float* __restrict__ Kmat,
                                            float* __restrict__ hr) {
    __shared__ __align__(16) float lds[16384];  // [0..4095]=K[q][pos], rest = feat strip [6][16][128]
    float* lK = lds;
    float* lF = lds + 4096;
    int bid = blockIdx.x;
    int b = bid >> 3;
    int y0 = (bid & 7) << 4;
    int tid = threadIdx.x;
    for (int i = tid; i < 4096; i += 256) lK[i] = Kmat[i];
    for (int i = tid; i < 12288; i += 256) {
        int c = i >> 11, rem = i & 2047;
        lF[i] = feat[(((size_t)b * NFEAT + c) << 14) + (((size_t)y0 + (rem >> 7)) << 7) + (rem & 127)];
    }
    __syncthreads();
    int tile = tid >> 3, hrow = tid & 7;
    int tr = tile >> 4, tx = tile & 15;
    float acc[6][8];
#pragma unroll
    for (int c = 0; c < 6; ++c)
#pragma unroll
        for (int j = 0; j < 8; ++j) acc[c][j] = 0.f;
    int fbase = (tr << 3) * 128 + (tx << 3);
    for (int q = 0; q < 64; ++q) {
        int iq = q >> 3, jq = q & 7;
        const float4 k0 = *(const float4*)&lK[(q << 6) + (hrow << 3)];
        const float4 k1 = *(const float4*)&lK[(q << 6) + (hrow << 3) + 4];
#pragma unroll
        for (int c = 0; c < 6; ++c) {
            float col = lF[(c << 11) + fbase + (iq << 7) + jq];
            acc[c][0] += col * k0.x; acc[c][1] += col * k0.y;
            acc[c][2] += col * k0.z; acc[c][3] += col * k0.w;
            acc[c][4] += col * k1.x; acc[c][5] += col * k1.y;
            acc[c][6] += col * k1.z; acc[c][7] += col * k1.w;
        }
    }
    int y = y0 + (tr << 3) + hrow;
#pragma unroll
    for (int c = 0; c < 6; ++c) {
        const float4* vp = (const float4*)(V + (((size_t)b * NFEAT + c) << 14) + ((size_t)y << 7) + (tx << 3));
        float4 v0 = vp[0], v1 = vp[1];
        float4 r0, r1;
        r0.x = acc[c][0] * v0.x; r0.y = acc[c][1] * v0.y; r0.z = acc[c][2] * v0.z; r0.w = acc[c][3] * v0.w;
        r1.x = acc[c][4] * v1.x; r1.y = acc[c][5] * v1.y; r1.z = acc[c][6] * v1.z; r1.w = acc[c][7] * v1.w;
        float4* op = (float4*)(hr + (((size_t)b * C1c + c) << 14) + ((size_t)y << 7) + (tx << 3));
        op[0] = r0; op[1] = r1;
    }
}

// ---------------- K5: final fused conv3x3(out_feat) + conv1x1(feat) + biases + up(ms) ----------------
__global__ __launch_bounds__(256) void k_conv(const float* __restrict__ feat,
                                              const float* __restrict__ V,
                                              const float* __restrict__ ms,
                                              const float* __restrict__ w_fine,
                                              const float* __restrict__ b_fine,
                                              const float* __restrict__ w_res,
                                              const float* __restrict__ b_res,
                                              const float* __restrict__ hr,
                                              const float* __restrict__ attn,
                                              float* __restrict__ out) {
    __shared__ float s_tile[18 * 18];
    __shared__ float s_wf[4 * 48 * 9];
    __shared__ float s_wr[4 * 48];
    __shared__ float s_attn[LRC];
    __shared__ float s_misc[8];
    int bid = blockIdx.x;
    int b = bid >> 6;
    int t64 = bid & 63;
    int ty0 = ((t64 >> 3) & 7) << 4;
    int tx0 = (t64 & 7) << 4;
    int tid = threadIdx.x;
    for (int i = tid; i < 1728; i += 256) s_wf[i] = w_fine[i];
    if (tid < 192) s_wr[tid] = w_res[tid];
    if (tid < LRC) s_attn[tid] = attn[b * LRC + tid];
    if (tid < 4) { s_misc[tid] = b_fine[tid]; s_misc[4 + tid] = b_res[tid]; }
    int lx = tid & 15, ly = tid >> 4;
    int gy = ty0 + ly, gx = tx0 + lx;
    float a0 = 0.f, a1 = 0.f, a2 = 0.f, a3 = 0.f;
    for (int c = 0; c < NFEAT; ++c) {
        __syncthreads();
        for (int i = tid; i < 324; i += 256) {
            int r = i / 18, cc = i % 18;
            int sy = ty0 - 1 + r, sx = tx0 - 1 + cc;
            float v = 0.f;
            if (sy >= 0 && sy < HH && sx >= 0 && sx < WW) {
                if (c < C1c) {
                    v = hr[(((size_t)b * C1c + c) << 14) + (sy << 7) + sx];
                } else {
                    size_t gi = (((size_t)b * NFEAT + c) << 14) + (sy << 7) + sx;
                    v = feat[gi] * s_attn[c - C1c] * V[gi];
                }
            }
            s_tile[i] = v;
        }
        __syncthreads();
        float fc = feat[(((size_t)b * NFEAT + c) << 14) + (gy << 7) + gx];
        a0 += s_wr[c] * fc; a1 += s_wr[48 + c] * fc; a2 += s_wr[96 + c] * fc; a3 += s_wr[144 + c] * fc;
#pragma unroll
        for (int dy = 0; dy < 3; ++dy)
#pragma unroll
            for (int dx = 0; dx < 3; ++dx) {
                float v = s_tile[(ly + dy) * 18 + lx + dx];
                int wi = c * 9 + dy * 3 + dx;
                a0 += s_wf[wi] * v;
                a1 += s_wf[432 + wi] * v;
                a2 += s_wf[864 + wi] * v;
                a3 += s_wf[1296 + wi] * v;
            }
    }
    // bilinear upsample of ms (32x32 -> 128x128), jax half-pixel + edge-clamp semantics
    float syf = (gy + 0.5f) * 0.25f - 0.5f;
    float sxf = (gx + 0.5f) * 0.25f - 0.5f;
    int y0i = (int)floorf(syf); float fy = syf - (float)y0i;
    int x0i = (int)floorf(sxf); float fx = sxf - (float)x0i;
    int y0c = min(31, max(0, y0i)), y1c = min(31, max(0, y0i + 1));
    int x0c = min(31, max(0, x0i)), x1c = min(31, max(0, x0i + 1));
    float accs[4] = {a0, a1, a2, a3};
#pragma unroll
    for (int o = 0; o < 4; ++o) {
        const float* mb = ms + ((size_t)b * 4 + o) * 1024;
        float m00 = mb[y0c * 32 + x0c], m01 = mb[y0c * 32 + x1c];
        float m10 = mb[y1c * 32 + x0c], m11 = mb[y1c * 32 + x1c];
        float up = (m00 * (1.f - fx) + m01 * fx) * (1.f - fy) + (m10 * (1.f - fx) + m11 * fx) * fy;
        out[(((size_t)b * 4 + o) << 14) + (gy << 7) + gx] = accs[o] + s_misc[o] + s_misc[4 + o] + up;
    }
}

extern "C" void kernel_launch(void* const* d_in, const int* in_sizes, int n_in,
                              void* d_out, int out_size, void* d_ws, size_t ws_size,
                              hipStream_t stream) {
    (void)in_sizes; (void)n_in; (void)out_size; (void)ws_size;
    const float* ms     = (const float*)d_in[0];
    const float* feat   = (const float*)d_in[1];
    const float* V      = (const float*)d_in[2];
    const float* logits = (const float*)d_in[3];
    const float* sigx   = (const float*)d_in[4];
    const float* sigy   = (const float*)d_in[5];
    const float* opac   = (const float*)d_in[6];
    const float* rho    = (const float*)d_in[7];
    const float* w_v2   = (const float*)d_in[8];
    const float* w_fine = (const float*)d_in[9];
    const float* b_fine = (const float*)d_in[10];
    const float* w_res  = (const float*)d_in[11];
    const float* b_res  = (const float*)d_in[12];
    float* ws  = (float*)d_ws;
    float* out = (float*)d_out;

    hipMemsetAsync(ws + OFF_PM, 0, (size_t)NP * NQ * sizeof(float), stream);
    k_softmax_pm<<<256, 512, 0, stream>>>(logits, ws + OFF_PM);
    k_gap<<<NBATCH * LRC, 256, 0, stream>>>(feat, ws + OFF_GAP);
    k_small<<<1, 256, 0, stream>>>(ws + OFF_PM, ws + OFF_GAP, sigx, sigy, opac, rho, w_v2,
                                   ws + OFF_K, ws + OFF_ATTN);
    k_hr<<<256, 256, 0, stream>>>(feat, V, ws + OFF_K, ws + OFF_HR);
    k_conv<<<2048, 256, 0, stream>>>(feat, V, ms, w_fine, b_fine, w_res, b_res,
                                     ws + OFF_HR, ws + OFF_ATTN, out);
}